// Round 7
// baseline (91.666 us; speedup 1.0000x reference)
//
#include <hip/hip_runtime.h>
#include <hip/hip_bf16.h>

typedef float  f32x4  __attribute__((ext_vector_type(4)));
typedef short  s16x8  __attribute__((ext_vector_type(8)));

__device__ __forceinline__ unsigned short f2bf(float f) {
    unsigned int u = __float_as_uint(f);
    unsigned int rnd = 0x7fffu + ((u >> 16) & 1u);   // round-to-nearest-even
    return (unsigned short)((u + rnd) >> 16);
}

// acc += s * unpack_bf16x8(v)
__device__ __forceinline__ void bf8_fma(const s16x8 v, float s, f32x4& a0, f32x4& a1) {
    const uint4 u = *(const uint4*)&v;
    a0[0] += s * __uint_as_float(u.x << 16);
    a0[1] += s * __uint_as_float(u.x & 0xffff0000u);
    a0[2] += s * __uint_as_float(u.y << 16);
    a0[3] += s * __uint_as_float(u.y & 0xffff0000u);
    a1[0] += s * __uint_as_float(u.z << 16);
    a1[1] += s * __uint_as_float(u.z & 0xffff0000u);
    a1[2] += s * __uint_as_float(u.w << 16);
    a1[3] += s * __uint_as_float(u.w & 0xffff0000u);
}

// Wq (f32 128x128) -> bf16 B-fragments, frag-linear.
// slot s: frag f=s>>6=jt*4+kt, sublane sl=s&63 holds Wq[jt*16+(sl&15)][kt*32+(sl>>4)*8+i], i<8.
__global__ __launch_bounds__(256)
void h2kt_prep_wqb(const float* __restrict__ Wq, unsigned short* __restrict__ Wqb) {
    const int s  = blockIdx.x * 256 + threadIdx.x;   // 0..2047
    const int f  = s >> 6, sl = s & 63;
    const int jt = f >> 2, kt = f & 3;
    const int row = jt * 16 + (sl & 15);
    const int col = kt * 32 + (sl >> 4) * 8;
    const float4 w0 = *(const float4*)(Wq + row * 128 + col);
    const float4 w1 = *(const float4*)(Wq + row * 128 + col + 4);
    s16x8 v;
    v[0] = (short)f2bf(w0.x); v[1] = (short)f2bf(w0.y);
    v[2] = (short)f2bf(w0.z); v[3] = (short)f2bf(w0.w);
    v[4] = (short)f2bf(w1.x); v[5] = (short)f2bf(w1.y);
    v[6] = (short)f2bf(w1.z); v[7] = (short)f2bf(w1.w);
    *(s16x8*)(Wqb + (size_t)s * 8) = v;
}

// Pre-transform small tables: T2[r] = table_row @ Wq^T (bf16 row-major).
// Unified rows: skill@0..2000, diff@2001..2100, area@2101..2150.
__global__ __launch_bounds__(64)
void h2kt_prep_tables(const float* __restrict__ skill, const float* __restrict__ diff,
                      const float* __restrict__ area, const unsigned short* __restrict__ Wqb,
                      unsigned short* __restrict__ T2)
{
    const int lane = threadIdx.x;
    const int cl = lane & 15, grp = lane >> 4;
    const int row16 = blockIdx.x * 16;

    int srow = row16 + cl;
    if (srow > 2150) srow = 2150;
    const float* src = (srow < 2001) ? skill + (size_t)srow * 128
                     : (srow < 2101) ? diff + (size_t)(srow - 2001) * 128
                                     : area + (size_t)(srow - 2101) * 128;
    s16x8 afr[4];
    #pragma unroll
    for (int kt = 0; kt < 4; ++kt) {
        const float4 v0 = *(const float4*)(src + kt * 32 + grp * 8);
        const float4 v1 = *(const float4*)(src + kt * 32 + grp * 8 + 4);
        s16x8 v;
        v[0] = (short)f2bf(v0.x); v[1] = (short)f2bf(v0.y);
        v[2] = (short)f2bf(v0.z); v[3] = (short)f2bf(v0.w);
        v[4] = (short)f2bf(v1.x); v[5] = (short)f2bf(v1.y);
        v[6] = (short)f2bf(v1.z); v[7] = (short)f2bf(v1.w);
        afr[kt] = v;
    }
    #pragma unroll
    for (int jt = 0; jt < 8; ++jt) {
        f32x4 acc = {0.f, 0.f, 0.f, 0.f};
        #pragma unroll
        for (int kt = 0; kt < 4; ++kt) {
            const s16x8 bf = *(const s16x8*)(Wqb + ((size_t)(jt * 4 + kt) * 64 + lane) * 8);
            acc = __builtin_amdgcn_mfma_f32_16x16x32_bf16(afr[kt], bf, acc, 0, 0, 0);
        }
        #pragma unroll
        for (int r = 0; r < 4; ++r) {
            const int orow = row16 + grp * 4 + r;
            if (orow < 2151) T2[(size_t)orow * 128 + jt * 16 + cl] = f2bf(acc[r]);
        }
    }
}

// Fused main (R4 structure + LDS union for 16 blocks/CU + vector-NT stores).
// 2 waves per 16-row tile; wave w owns rows w*8..w*8+7 for row-major phases
// and jt-cols w*4..w*4+3 for the MFMA phase.
__global__ __launch_bounds__(128, 8)
void h2kt_fused(const int* __restrict__ q, const int* __restrict__ a_arr,
                const int* __restrict__ next_q,
                const float* __restrict__ ques_table,
                const int* __restrict__ q2s,
                const int* __restrict__ q2d,
                const int* __restrict__ q2a,
                const unsigned short* __restrict__ T2,
                const unsigned short* __restrict__ Wqb,
                const float* __restrict__ bq,
                float* __restrict__ out,
                int pad_idx)
{
    // Q (bf16 16x136) and D (f32 16x132) are live in disjoint phases -> union.
    __shared__ __align__(16) unsigned char U[16 * 132 * 4];   // 8448 B
    unsigned short* Q = (unsigned short*)U;    // stride 136 (272 B, 16-B aligned)
    float*          D = (float*)U;             // stride 132 (528 B, 16-B aligned)

    const int tid  = threadIdx.x;
    const int w    = tid >> 6;
    const int lane = tid & 63;
    const int cl   = lane & 15;
    const int grp  = lane >> 4;
    const int r0   = blockIdx.x * 16;
    const int base = r0 & 32767;
    const bool isnq = (r0 >= 32768);
    const int* __restrict__ QQ = isnq ? next_q : q;
    const float wq_ = isnq ? 0.0625f : 0.25f;
    const float wr_ = isnq ? 0.3125f : 0.25f;

    // ---- qe gather, ROW-major (2 rows/instr, contiguous); NT loads (no L2 reuse)
    {
        const int r2 = lane >> 5;          // 0/1
        const int c  = lane & 31;          // f32x4 chunk (cols 4c..4c+3)
        int qqv[4];
        #pragma unroll
        for (int p = 0; p < 4; ++p) qqv[p] = QQ[base + w * 8 + p * 2 + r2];
        #pragma unroll
        for (int p = 0; p < 4; ++p) {
            const f32x4 v = __builtin_nontemporal_load(
                (const f32x4*)(ques_table + (size_t)qqv[p] * 128 + c * 4));
            ushort4 o;
            o.x = f2bf(wq_ * v[0]); o.y = f2bf(wq_ * v[1]);
            o.z = f2bf(wq_ * v[2]); o.w = f2bf(wq_ * v[3]);
            *(ushort4*)(Q + (size_t)(w * 8 + p * 2 + r2) * 136 + c * 4) = o;
        }
    }

    // ---- rest gather, ROW-major (4 rows/pass; lane: row=grp, chunk=cl -> 8 cols)
    f32x4 restA[2], restB[2];
    int avv[2] = {1, 1};
    #pragma unroll
    for (int p = 0; p < 2; ++p) {
        const int row = w * 8 + p * 4 + grp;
        const int pq  = base + row;
        const int qq2 = QQ[pq];
        if (!isnq) avv[p] = a_arr[pq];
        const int4 s03 = *(const int4*)(q2s + (size_t)qq2 * 8);
        const int4 s47 = *(const int4*)(q2s + (size_t)qq2 * 8 + 4);
        const int di = q2d[qq2];
        const int ai = q2a[qq2];
        const int sidx[8] = {s03.x, s03.y, s03.z, s03.w, s47.x, s47.y, s47.z, s47.w};
        int cnt = 0;
        #pragma unroll
        for (int i = 0; i < 8; ++i) cnt += (sidx[i] != pad_idx);
        const float cs = cnt > 0 ? wr_ / (float)cnt : 0.f;

        f32x4 a0 = {0.f, 0.f, 0.f, 0.f}, a1 = {0.f, 0.f, 0.f, 0.f};
        #pragma unroll
        for (int i = 0; i < 8; ++i) {
            const s16x8 sv = *(const s16x8*)(T2 + (size_t)sidx[i] * 128 + cl * 8);
            bf8_fma(sv, (sidx[i] != pad_idx) ? cs : 0.f, a0, a1);
        }
        bf8_fma(*(const s16x8*)(T2 + (size_t)(2001 + di) * 128 + cl * 8), wr_, a0, a1);
        bf8_fma(*(const s16x8*)(T2 + (size_t)(2101 + ai) * 128 + cl * 8), wr_, a0, a1);
        restA[p] = a0; restB[p] = a1;
    }

    __syncthreads();   // Q ready

    // ---- A-frags from LDS ----
    s16x8 afr[4];
    #pragma unroll
    for (int kt = 0; kt < 4; ++kt)
        afr[kt] = *(const s16x8*)(Q + (size_t)cl * 136 + kt * 32 + grp * 8);

    __syncthreads();   // Q fully consumed -> D may overwrite the union

    // ---- MFMA (wave w does jt = w*4..w*4+3) -> D ----
    #pragma unroll
    for (int jt2 = 0; jt2 < 4; ++jt2) {
        const int jt = w * 4 + jt2;
        f32x4 acc = {0.f, 0.f, 0.f, 0.f};
        #pragma unroll
        for (int kt = 0; kt < 4; ++kt) {
            const s16x8 bf = *(const s16x8*)(Wqb + ((size_t)(jt * 4 + kt) * 64 + lane) * 8);
            acc = __builtin_amdgcn_mfma_f32_16x16x32_bf16(afr[kt], bf, acc, 0, 0, 0);
        }
        #pragma unroll
        for (int r = 0; r < 4; ++r)
            D[(size_t)(grp * 4 + r) * 132 + jt * 16 + cl] = acc[r];
    }

    __syncthreads();   // D ready

    // ---- epilogue: row-major combine + masked concat, vector NT stores ----
    const f32x4 bq0 = *(const f32x4*)(bq + cl * 8);
    const f32x4 bq1 = *(const f32x4*)(bq + cl * 8 + 4);
    const f32x4 z = {0.f, 0.f, 0.f, 0.f};
    #pragma unroll
    for (int p = 0; p < 2; ++p) {
        const int row = w * 8 + p * 4 + grp;
        const f32x4 d0 = *(const f32x4*)(D + (size_t)row * 132 + cl * 8);
        const f32x4 d1 = *(const f32x4*)(D + (size_t)row * 132 + cl * 8 + 4);
        const f32x4 v0 = d0 + restA[p] + bq0;
        const f32x4 v1 = d1 + restB[p] + bq1;
        const size_t orow = (size_t)(base + row);
        if (!isnq) {
            const bool on = (avv[p] != 0);
            __builtin_nontemporal_store(on ? v0 : z, (f32x4*)(out + orow * 384 + cl * 8));
            __builtin_nontemporal_store(on ? v1 : z, (f32x4*)(out + orow * 384 + cl * 8 + 4));
            __builtin_nontemporal_store(on ? z : v0, (f32x4*)(out + orow * 384 + 128 + cl * 8));
            __builtin_nontemporal_store(on ? z : v1, (f32x4*)(out + orow * 384 + 128 + cl * 8 + 4));
        } else {
            __builtin_nontemporal_store(v0, (f32x4*)(out + orow * 384 + 256 + cl * 8));
            __builtin_nontemporal_store(v1, (f32x4*)(out + orow * 384 + 256 + cl * 8 + 4));
        }
    }
}

extern "C" void kernel_launch(void* const* d_in, const int* in_sizes, int n_in,
                              void* d_out, int out_size, void* d_ws, size_t ws_size,
                              hipStream_t stream) {
    const int*   q          = (const int*)d_in[0];
    const int*   a          = (const int*)d_in[1];
    const int*   next_q     = (const int*)d_in[2];
    const float* ques_table = (const float*)d_in[3];
    const float* skill_tab  = (const float*)d_in[4];
    const float* diff_tab   = (const float*)d_in[5];
    const float* area_tab   = (const float*)d_in[6];
    const int*   q2s        = (const int*)d_in[7];
    const int*   q2d        = (const int*)d_in[8];
    const int*   q2a        = (const int*)d_in[9];
    const float* Wq         = (const float*)d_in[10];
    const float* bq         = (const float*)d_in[11];
    float* out = (float*)d_out;

    const int NS = in_sizes[4] / 128;       // 2001
    const int pad_idx = NS - 1;             // 2000

    unsigned short* Wqb = (unsigned short*)d_ws;            // 2048*8 = 32 KiB
    unsigned short* T2  = Wqb + (size_t)2048 * 8;           // 2151*128 bf16

    h2kt_prep_wqb<<<8, 256, 0, stream>>>(Wq, Wqb);
    h2kt_prep_tables<<<135, 64, 0, stream>>>(skill_tab, diff_tab, area_tab, Wqb, T2);
    h2kt_fused<<<4096, 128, 0, stream>>>(q, a, next_q, ques_table,
                                         q2s, q2d, q2a, T2, Wqb, bq, out, pad_idx);
}

// Round 8
// 86.945 us; speedup vs baseline: 1.0543x; 1.0543x over previous
//
#include <hip/hip_runtime.h>
#include <hip/hip_bf16.h>

typedef float  f32x4  __attribute__((ext_vector_type(4)));
typedef short  s16x8  __attribute__((ext_vector_type(8)));

__device__ __forceinline__ unsigned short f2bf(float f) {
    unsigned int u = __float_as_uint(f);
    unsigned int rnd = 0x7fffu + ((u >> 16) & 1u);   // round-to-nearest-even
    return (unsigned short)((u + rnd) >> 16);
}

// acc += s * unpack_bf16x8(v)
__device__ __forceinline__ void bf8_fma(const s16x8 v, float s, f32x4& a0, f32x4& a1) {
    const uint4 u = *(const uint4*)&v;
    a0[0] += s * __uint_as_float(u.x << 16);
    a0[1] += s * __uint_as_float(u.x & 0xffff0000u);
    a0[2] += s * __uint_as_float(u.y << 16);
    a0[3] += s * __uint_as_float(u.y & 0xffff0000u);
    a1[0] += s * __uint_as_float(u.z << 16);
    a1[1] += s * __uint_as_float(u.z & 0xffff0000u);
    a1[2] += s * __uint_as_float(u.w << 16);
    a1[3] += s * __uint_as_float(u.w & 0xffff0000u);
}

// Wq (f32 128x128) -> bf16 B-fragments, frag-linear.
// slot s: frag f=s>>6=jt*4+kt, sublane sl=s&63 holds Wq[jt*16+(sl&15)][kt*32+(sl>>4)*8+i], i<8.
__global__ __launch_bounds__(256)
void h2kt_prep_wqb(const float* __restrict__ Wq, unsigned short* __restrict__ Wqb) {
    const int s  = blockIdx.x * 256 + threadIdx.x;   // 0..2047
    const int f  = s >> 6, sl = s & 63;
    const int jt = f >> 2, kt = f & 3;
    const int row = jt * 16 + (sl & 15);
    const int col = kt * 32 + (sl >> 4) * 8;
    const float4 w0 = *(const float4*)(Wq + row * 128 + col);
    const float4 w1 = *(const float4*)(Wq + row * 128 + col + 4);
    s16x8 v;
    v[0] = (short)f2bf(w0.x); v[1] = (short)f2bf(w0.y);
    v[2] = (short)f2bf(w0.z); v[3] = (short)f2bf(w0.w);
    v[4] = (short)f2bf(w1.x); v[5] = (short)f2bf(w1.y);
    v[6] = (short)f2bf(w1.z); v[7] = (short)f2bf(w1.w);
    *(s16x8*)(Wqb + (size_t)s * 8) = v;
}

// Pre-transform small tables: T2[r] = table_row @ Wq^T (bf16 row-major).
// Unified rows: skill@0..2000, diff@2001..2100, area@2101..2150.
__global__ __launch_bounds__(64)
void h2kt_prep_tables(const float* __restrict__ skill, const float* __restrict__ diff,
                      const float* __restrict__ area, const unsigned short* __restrict__ Wqb,
                      unsigned short* __restrict__ T2)
{
    const int lane = threadIdx.x;
    const int cl = lane & 15, grp = lane >> 4;
    const int row16 = blockIdx.x * 16;

    int srow = row16 + cl;
    if (srow > 2150) srow = 2150;
    const float* src = (srow < 2001) ? skill + (size_t)srow * 128
                     : (srow < 2101) ? diff + (size_t)(srow - 2001) * 128
                                     : area + (size_t)(srow - 2101) * 128;
    s16x8 afr[4];
    #pragma unroll
    for (int kt = 0; kt < 4; ++kt) {
        const float4 v0 = *(const float4*)(src + kt * 32 + grp * 8);
        const float4 v1 = *(const float4*)(src + kt * 32 + grp * 8 + 4);
        s16x8 v;
        v[0] = (short)f2bf(v0.x); v[1] = (short)f2bf(v0.y);
        v[2] = (short)f2bf(v0.z); v[3] = (short)f2bf(v0.w);
        v[4] = (short)f2bf(v1.x); v[5] = (short)f2bf(v1.y);
        v[6] = (short)f2bf(v1.z); v[7] = (short)f2bf(v1.w);
        afr[kt] = v;
    }
    #pragma unroll
    for (int jt = 0; jt < 8; ++jt) {
        f32x4 acc = {0.f, 0.f, 0.f, 0.f};
        #pragma unroll
        for (int kt = 0; kt < 4; ++kt) {
            const s16x8 bf = *(const s16x8*)(Wqb + ((size_t)(jt * 4 + kt) * 64 + lane) * 8);
            acc = __builtin_amdgcn_mfma_f32_16x16x32_bf16(afr[kt], bf, acc, 0, 0, 0);
        }
        #pragma unroll
        for (int r = 0; r < 4; ++r) {
            const int orow = row16 + grp * 4 + r;
            if (orow < 2151) T2[(size_t)orow * 128 + jt * 16 + cl] = f2bf(acc[r]);
        }
    }
}

// Fused main: R4 structure + LDS union (16 blocks/CU) -- NO nontemporal hints
// (R7 showed NT sparse stores cause RMW write-amplification: WRITE 53->229 MB).
// 2 waves per 16-row tile; wave w owns rows w*8..w*8+7 for row-major phases
// and jt-cols w*4..w*4+3 for the MFMA phase.
__global__ __launch_bounds__(128, 8)
void h2kt_fused(const int* __restrict__ q, const int* __restrict__ a_arr,
                const int* __restrict__ next_q,
                const float* __restrict__ ques_table,
                const int* __restrict__ q2s,
                const int* __restrict__ q2d,
                const int* __restrict__ q2a,
                const unsigned short* __restrict__ T2,
                const unsigned short* __restrict__ Wqb,
                const float* __restrict__ bq,
                float* __restrict__ out,
                int pad_idx)
{
    // Q (bf16 16x136) and D (f32 16x132) are live in disjoint phases -> union.
    __shared__ __align__(16) unsigned char U[16 * 132 * 4];   // 8448 B
    unsigned short* Q = (unsigned short*)U;    // stride 136 (272 B, 16-B aligned)
    float*          D = (float*)U;             // stride 132 (528 B, 16-B aligned)

    const int tid  = threadIdx.x;
    const int w    = tid >> 6;
    const int lane = tid & 63;
    const int cl   = lane & 15;
    const int grp  = lane >> 4;
    const int r0   = blockIdx.x * 16;
    const int base = r0 & 32767;
    const bool isnq = (r0 >= 32768);
    const int* __restrict__ QQ = isnq ? next_q : q;
    const float wq_ = isnq ? 0.0625f : 0.25f;
    const float wr_ = isnq ? 0.3125f : 0.25f;

    // ---- qe gather, ROW-major (2 rows/instr, contiguous) -> bf16(wq*qe) -> LDS Q
    {
        const int r2 = lane >> 5;          // 0/1
        const int c  = lane & 31;          // f32x4 chunk (cols 4c..4c+3)
        int qqv[4];
        #pragma unroll
        for (int p = 0; p < 4; ++p) qqv[p] = QQ[base + w * 8 + p * 2 + r2];
        #pragma unroll
        for (int p = 0; p < 4; ++p) {
            const f32x4 v = *(const f32x4*)(ques_table + (size_t)qqv[p] * 128 + c * 4);
            ushort4 o;
            o.x = f2bf(wq_ * v[0]); o.y = f2bf(wq_ * v[1]);
            o.z = f2bf(wq_ * v[2]); o.w = f2bf(wq_ * v[3]);
            *(ushort4*)(Q + (size_t)(w * 8 + p * 2 + r2) * 136 + c * 4) = o;
        }
    }

    // ---- rest gather, ROW-major (4 rows/pass; lane: row=grp, chunk=cl -> 8 cols)
    f32x4 restA[2], restB[2];
    int avv[2] = {1, 1};
    #pragma unroll
    for (int p = 0; p < 2; ++p) {
        const int row = w * 8 + p * 4 + grp;
        const int pq  = base + row;
        const int qq2 = QQ[pq];
        if (!isnq) avv[p] = a_arr[pq];
        const int4 s03 = *(const int4*)(q2s + (size_t)qq2 * 8);
        const int4 s47 = *(const int4*)(q2s + (size_t)qq2 * 8 + 4);
        const int di = q2d[qq2];
        const int ai = q2a[qq2];
        const int sidx[8] = {s03.x, s03.y, s03.z, s03.w, s47.x, s47.y, s47.z, s47.w};
        int cnt = 0;
        #pragma unroll
        for (int i = 0; i < 8; ++i) cnt += (sidx[i] != pad_idx);
        const float cs = cnt > 0 ? wr_ / (float)cnt : 0.f;

        f32x4 a0 = {0.f, 0.f, 0.f, 0.f}, a1 = {0.f, 0.f, 0.f, 0.f};
        #pragma unroll
        for (int i = 0; i < 8; ++i) {
            const s16x8 sv = *(const s16x8*)(T2 + (size_t)sidx[i] * 128 + cl * 8);
            bf8_fma(sv, (sidx[i] != pad_idx) ? cs : 0.f, a0, a1);
        }
        bf8_fma(*(const s16x8*)(T2 + (size_t)(2001 + di) * 128 + cl * 8), wr_, a0, a1);
        bf8_fma(*(const s16x8*)(T2 + (size_t)(2101 + ai) * 128 + cl * 8), wr_, a0, a1);
        restA[p] = a0; restB[p] = a1;
    }

    __syncthreads();   // Q ready

    // ---- A-frags from LDS ----
    s16x8 afr[4];
    #pragma unroll
    for (int kt = 0; kt < 4; ++kt)
        afr[kt] = *(const s16x8*)(Q + (size_t)cl * 136 + kt * 32 + grp * 8);

    __syncthreads();   // Q fully consumed -> D may overwrite the union

    // ---- MFMA (wave w does jt = w*4..w*4+3) -> D ----
    #pragma unroll
    for (int jt2 = 0; jt2 < 4; ++jt2) {
        const int jt = w * 4 + jt2;
        f32x4 acc = {0.f, 0.f, 0.f, 0.f};
        #pragma unroll
        for (int kt = 0; kt < 4; ++kt) {
            const s16x8 bf = *(const s16x8*)(Wqb + ((size_t)(jt * 4 + kt) * 64 + lane) * 8);
            acc = __builtin_amdgcn_mfma_f32_16x16x32_bf16(afr[kt], bf, acc, 0, 0, 0);
        }
        #pragma unroll
        for (int r = 0; r < 4; ++r)
            D[(size_t)(grp * 4 + r) * 132 + jt * 16 + cl] = acc[r];
    }

    __syncthreads();   // D ready

    // ---- epilogue: row-major combine + masked concat, plain vector stores ----
    const f32x4 bq0 = *(const f32x4*)(bq + cl * 8);
    const f32x4 bq1 = *(const f32x4*)(bq + cl * 8 + 4);
    const f32x4 z = {0.f, 0.f, 0.f, 0.f};
    #pragma unroll
    for (int p = 0; p < 2; ++p) {
        const int row = w * 8 + p * 4 + grp;
        const f32x4 d0 = *(const f32x4*)(D + (size_t)row * 132 + cl * 8);
        const f32x4 d1 = *(const f32x4*)(D + (size_t)row * 132 + cl * 8 + 4);
        const f32x4 v0 = d0 + restA[p] + bq0;
        const f32x4 v1 = d1 + restB[p] + bq1;
        const size_t orow = (size_t)(base + row);
        if (!isnq) {
            const bool on = (avv[p] != 0);
            *(f32x4*)(out + orow * 384 + cl * 8)           = on ? v0 : z;
            *(f32x4*)(out + orow * 384 + cl * 8 + 4)       = on ? v1 : z;
            *(f32x4*)(out + orow * 384 + 128 + cl * 8)     = on ? z : v0;
            *(f32x4*)(out + orow * 384 + 128 + cl * 8 + 4) = on ? z : v1;
        } else {
            *(f32x4*)(out + orow * 384 + 256 + cl * 8)     = v0;
            *(f32x4*)(out + orow * 384 + 256 + cl * 8 + 4) = v1;
        }
    }
}

extern "C" void kernel_launch(void* const* d_in, const int* in_sizes, int n_in,
                              void* d_out, int out_size, void* d_ws, size_t ws_size,
                              hipStream_t stream) {
    const int*   q          = (const int*)d_in[0];
    const int*   a          = (const int*)d_in[1];
    const int*   next_q     = (const int*)d_in[2];
    const float* ques_table = (const float*)d_in[3];
    const float* skill_tab  = (const float*)d_in[4];
    const float* diff_tab   = (const float*)d_in[5];
    const float* area_tab   = (const float*)d_in[6];
    const int*   q2s        = (const int*)d_in[7];
    const int*   q2d        = (const int*)d_in[8];
    const int*   q2a        = (const int*)d_in[9];
    const float* Wq         = (const float*)d_in[10];
    const float* bq         = (const float*)d_in[11];
    float* out = (float*)d_out;

    const int NS = in_sizes[4] / 128;       // 2001
    const int pad_idx = NS - 1;             // 2000

    unsigned short* Wqb = (unsigned short*)d_ws;            // 2048*8 = 32 KiB
    unsigned short* T2  = Wqb + (size_t)2048 * 8;           // 2151*128 bf16

    h2kt_prep_wqb<<<8, 256, 0, stream>>>(Wq, Wqb);
    h2kt_prep_tables<<<135, 64, 0, stream>>>(skill_tab, diff_tab, area_tab, Wqb, T2);
    h2kt_fused<<<4096, 128, 0, stream>>>(q, a, next_q, ques_table,
                                         q2s, q2d, q2a, T2, Wqb, bq, out, pad_idx);
}

// Round 9
// 44.777 us; speedup vs baseline: 2.0471x; 1.9417x over previous
//
#include <hip/hip_runtime.h>
#include <hip/hip_bf16.h>

typedef float  f32x4  __attribute__((ext_vector_type(4)));
typedef short  s16x8  __attribute__((ext_vector_type(8)));

// compiler-level fence: memory ops cannot be moved across (pins issued loads)
#define PIN_LOADS() asm volatile("" ::: "memory")

__device__ __forceinline__ unsigned short f2bf(float f) {
    unsigned int u = __float_as_uint(f);
    unsigned int rnd = 0x7fffu + ((u >> 16) & 1u);   // round-to-nearest-even
    return (unsigned short)((u + rnd) >> 16);
}

// acc += s * unpack_bf16x8(v)
__device__ __forceinline__ void bf8_fma(const s16x8 v, float s, f32x4& a0, f32x4& a1) {
    const uint4 u = *(const uint4*)&v;
    a0[0] += s * __uint_as_float(u.x << 16);
    a0[1] += s * __uint_as_float(u.x & 0xffff0000u);
    a0[2] += s * __uint_as_float(u.y << 16);
    a0[3] += s * __uint_as_float(u.y & 0xffff0000u);
    a1[0] += s * __uint_as_float(u.z << 16);
    a1[1] += s * __uint_as_float(u.z & 0xffff0000u);
    a1[2] += s * __uint_as_float(u.w << 16);
    a1[3] += s * __uint_as_float(u.w & 0xffff0000u);
}

// Wq (f32 128x128) -> bf16 B-fragments, frag-linear.
__global__ __launch_bounds__(256)
void h2kt_prep_wqb(const float* __restrict__ Wq, unsigned short* __restrict__ Wqb) {
    const int s  = blockIdx.x * 256 + threadIdx.x;   // 0..2047
    const int f  = s >> 6, sl = s & 63;
    const int jt = f >> 2, kt = f & 3;
    const int row = jt * 16 + (sl & 15);
    const int col = kt * 32 + (sl >> 4) * 8;
    const float4 w0 = *(const float4*)(Wq + row * 128 + col);
    const float4 w1 = *(const float4*)(Wq + row * 128 + col + 4);
    s16x8 v;
    v[0] = (short)f2bf(w0.x); v[1] = (short)f2bf(w0.y);
    v[2] = (short)f2bf(w0.z); v[3] = (short)f2bf(w0.w);
    v[4] = (short)f2bf(w1.x); v[5] = (short)f2bf(w1.y);
    v[6] = (short)f2bf(w1.z); v[7] = (short)f2bf(w1.w);
    *(s16x8*)(Wqb + (size_t)s * 8) = v;
}

// Pre-transform small tables: T2[r] = table_row @ Wq^T (bf16 row-major).
// Unified rows: skill@0..2000, diff@2001..2100, area@2101..2150.
__global__ __launch_bounds__(64)
void h2kt_prep_tables(const float* __restrict__ skill, const float* __restrict__ diff,
                      const float* __restrict__ area, const unsigned short* __restrict__ Wqb,
                      unsigned short* __restrict__ T2)
{
    const int lane = threadIdx.x;
    const int cl = lane & 15, grp = lane >> 4;
    const int row16 = blockIdx.x * 16;

    int srow = row16 + cl;
    if (srow > 2150) srow = 2150;
    const float* src = (srow < 2001) ? skill + (size_t)srow * 128
                     : (srow < 2101) ? diff + (size_t)(srow - 2001) * 128
                                     : area + (size_t)(srow - 2101) * 128;
    s16x8 afr[4];
    #pragma unroll
    for (int kt = 0; kt < 4; ++kt) {
        const float4 v0 = *(const float4*)(src + kt * 32 + grp * 8);
        const float4 v1 = *(const float4*)(src + kt * 32 + grp * 8 + 4);
        s16x8 v;
        v[0] = (short)f2bf(v0.x); v[1] = (short)f2bf(v0.y);
        v[2] = (short)f2bf(v0.z); v[3] = (short)f2bf(v0.w);
        v[4] = (short)f2bf(v1.x); v[5] = (short)f2bf(v1.y);
        v[6] = (short)f2bf(v1.z); v[7] = (short)f2bf(v1.w);
        afr[kt] = v;
    }
    #pragma unroll
    for (int jt = 0; jt < 8; ++jt) {
        f32x4 acc = {0.f, 0.f, 0.f, 0.f};
        #pragma unroll
        for (int kt = 0; kt < 4; ++kt) {
            const s16x8 bf = *(const s16x8*)(Wqb + ((size_t)(jt * 4 + kt) * 64 + lane) * 8);
            acc = __builtin_amdgcn_mfma_f32_16x16x32_bf16(afr[kt], bf, acc, 0, 0, 0);
        }
        #pragma unroll
        for (int r = 0; r < 4; ++r) {
            const int orow = row16 + grp * 4 + r;
            if (orow < 2151) T2[(size_t)orow * 128 + jt * 16 + cl] = f2bf(acc[r]);
        }
    }
}

// Fused main: R4 structure (44.35 us baseline) + LDS union + PINNED batched
// gathers. launch_bounds(128,4): 128-VGPR cap -- R8 proved (128,8)/VGPR=32
// causes scratch spills (FETCH 30->116 MB, WRITE 53->209 MB).
__global__ __launch_bounds__(128, 4)
void h2kt_fused(const int* __restrict__ q, const int* __restrict__ a_arr,
                const int* __restrict__ next_q,
                const float* __restrict__ ques_table,
                const int* __restrict__ q2s,
                const int* __restrict__ q2d,
                const int* __restrict__ q2a,
                const unsigned short* __restrict__ T2,
                const unsigned short* __restrict__ Wqb,
                const float* __restrict__ bq,
                float* __restrict__ out,
                int pad_idx)
{
    // Q (bf16 16x136) and D (f32 16x132) live in disjoint phases -> union.
    __shared__ __align__(16) unsigned char U[16 * 132 * 4];   // 8448 B
    unsigned short* Q = (unsigned short*)U;    // stride 136 shorts
    float*          D = (float*)U;             // stride 132 floats

    const int tid  = threadIdx.x;
    const int w    = tid >> 6;
    const int lane = tid & 63;
    const int cl   = lane & 15;
    const int grp  = lane >> 4;
    const int r0   = blockIdx.x * 16;
    const int base = r0 & 32767;
    const bool isnq = (r0 >= 32768);
    const int* __restrict__ QQ = isnq ? next_q : q;
    const float wq_ = isnq ? 0.0625f : 0.25f;
    const float wr_ = isnq ? 0.3125f : 0.25f;

    // ---- all index loads ----
    const int r2 = lane >> 5;
    const int c  = lane & 31;
    int qqv[4];
    #pragma unroll
    for (int p = 0; p < 4; ++p) qqv[p] = QQ[base + w * 8 + p * 2 + r2];

    const int row0 = w * 8 + grp;
    const int row1 = w * 8 + 4 + grp;
    const int qq20 = QQ[base + row0];
    const int qq21 = QQ[base + row1];
    int av0 = 1, av1 = 1;
    if (!isnq) { av0 = a_arr[base + row0]; av1 = a_arr[base + row1]; }

    // ---- qe rows (HBM latency) issued ASAP ----
    f32x4 qv[4];
    #pragma unroll
    for (int p = 0; p < 4; ++p)
        qv[p] = *(const f32x4*)(ques_table + (size_t)qqv[p] * 128 + c * 4);

    // ---- second-level indices ----
    const int4 A03 = *(const int4*)(q2s + (size_t)qq20 * 8);
    const int4 A47 = *(const int4*)(q2s + (size_t)qq20 * 8 + 4);
    const int4 B03 = *(const int4*)(q2s + (size_t)qq21 * 8);
    const int4 B47 = *(const int4*)(q2s + (size_t)qq21 * 8 + 4);
    const int di0 = q2d[qq20], ai0 = q2a[qq20];
    const int di1 = q2d[qq21], ai1 = q2a[qq21];
    const int sa[8] = {A03.x, A03.y, A03.z, A03.w, A47.x, A47.y, A47.z, A47.w};
    const int sb[8] = {B03.x, B03.y, B03.z, B03.w, B47.x, B47.y, B47.z, B47.w};

    // ---- batch 0: pass-0 T2 slices (10 loads in flight) ----
    s16x8 t0[10];
    #pragma unroll
    for (int i = 0; i < 8; ++i)
        t0[i] = *(const s16x8*)(T2 + (size_t)sa[i] * 128 + cl * 8);
    t0[8] = *(const s16x8*)(T2 + (size_t)(2001 + di0) * 128 + cl * 8);
    t0[9] = *(const s16x8*)(T2 + (size_t)(2101 + ai0) * 128 + cl * 8);
    PIN_LOADS();   // forbid sinking: keep all 10 issued here

    // ---- qe -> bf16(wq*qe) -> LDS Q (consumes qv: frees 16 VGPR) ----
    #pragma unroll
    for (int p = 0; p < 4; ++p) {
        ushort4 o;
        o.x = f2bf(wq_ * qv[p][0]); o.y = f2bf(wq_ * qv[p][1]);
        o.z = f2bf(wq_ * qv[p][2]); o.w = f2bf(wq_ * qv[p][3]);
        *(ushort4*)(Q + (size_t)(w * 8 + p * 2 + r2) * 136 + c * 4) = o;
    }

    // ---- batch 1: pass-1 T2 slices issued before batch 0 is consumed ----
    s16x8 t1[10];
    #pragma unroll
    for (int i = 0; i < 8; ++i)
        t1[i] = *(const s16x8*)(T2 + (size_t)sb[i] * 128 + cl * 8);
    t1[8] = *(const s16x8*)(T2 + (size_t)(2001 + di1) * 128 + cl * 8);
    t1[9] = *(const s16x8*)(T2 + (size_t)(2101 + ai1) * 128 + cl * 8);
    PIN_LOADS();

    // ---- combine ----
    int cnt0 = 0, cnt1 = 0;
    #pragma unroll
    for (int i = 0; i < 8; ++i) { cnt0 += (sa[i] != pad_idx); cnt1 += (sb[i] != pad_idx); }
    const float cs0 = cnt0 > 0 ? wr_ / (float)cnt0 : 0.f;
    const float cs1 = cnt1 > 0 ? wr_ / (float)cnt1 : 0.f;

    f32x4 restA[2], restB[2];
    {
        f32x4 a0 = {0.f,0.f,0.f,0.f}, a1 = {0.f,0.f,0.f,0.f};
        #pragma unroll
        for (int i = 0; i < 8; ++i) bf8_fma(t0[i], (sa[i] != pad_idx) ? cs0 : 0.f, a0, a1);
        bf8_fma(t0[8], wr_, a0, a1);
        bf8_fma(t0[9], wr_, a0, a1);
        restA[0] = a0; restB[0] = a1;
    }
    {
        f32x4 a0 = {0.f,0.f,0.f,0.f}, a1 = {0.f,0.f,0.f,0.f};
        #pragma unroll
        for (int i = 0; i < 8; ++i) bf8_fma(t1[i], (sb[i] != pad_idx) ? cs1 : 0.f, a0, a1);
        bf8_fma(t1[8], wr_, a0, a1);
        bf8_fma(t1[9], wr_, a0, a1);
        restA[1] = a0; restB[1] = a1;
    }

    __syncthreads();   // Q ready

    // ---- A-frags from LDS ----
    s16x8 afr[4];
    #pragma unroll
    for (int kt = 0; kt < 4; ++kt)
        afr[kt] = *(const s16x8*)(Q + (size_t)cl * 136 + kt * 32 + grp * 8);

    __syncthreads();   // Q consumed -> D may overwrite the union

    // ---- MFMA (wave w does jt = w*4..w*4+3) -> D ----
    #pragma unroll
    for (int jt2 = 0; jt2 < 4; ++jt2) {
        const int jt = w * 4 + jt2;
        f32x4 acc = {0.f, 0.f, 0.f, 0.f};
        #pragma unroll
        for (int kt = 0; kt < 4; ++kt) {
            const s16x8 bf = *(const s16x8*)(Wqb + ((size_t)(jt * 4 + kt) * 64 + lane) * 8);
            acc = __builtin_amdgcn_mfma_f32_16x16x32_bf16(afr[kt], bf, acc, 0, 0, 0);
        }
        #pragma unroll
        for (int r = 0; r < 4; ++r)
            D[(size_t)(grp * 4 + r) * 132 + jt * 16 + cl] = acc[r];
    }

    __syncthreads();   // D ready

    // ---- epilogue: row-major combine + masked concat, plain vector stores ----
    const f32x4 bq0 = *(const f32x4*)(bq + cl * 8);
    const f32x4 bq1 = *(const f32x4*)(bq + cl * 8 + 4);
    const f32x4 z = {0.f, 0.f, 0.f, 0.f};
    #pragma unroll
    for (int p = 0; p < 2; ++p) {
        const int row = w * 8 + p * 4 + grp;
        const f32x4 d0 = *(const f32x4*)(D + (size_t)row * 132 + cl * 8);
        const f32x4 d1 = *(const f32x4*)(D + (size_t)row * 132 + cl * 8 + 4);
        const f32x4 v0 = d0 + restA[p] + bq0;
        const f32x4 v1 = d1 + restB[p] + bq1;
        const size_t orow = (size_t)(base + row);
        const int avv = (p == 0) ? av0 : av1;
        if (!isnq) {
            const bool on = (avv != 0);
            *(f32x4*)(out + orow * 384 + cl * 8)           = on ? v0 : z;
            *(f32x4*)(out + orow * 384 + cl * 8 + 4)       = on ? v1 : z;
            *(f32x4*)(out + orow * 384 + 128 + cl * 8)     = on ? z : v0;
            *(f32x4*)(out + orow * 384 + 128 + cl * 8 + 4) = on ? z : v1;
        } else {
            *(f32x4*)(out + orow * 384 + 256 + cl * 8)     = v0;
            *(f32x4*)(out + orow * 384 + 256 + cl * 8 + 4) = v1;
        }
    }
}

extern "C" void kernel_launch(void* const* d_in, const int* in_sizes, int n_in,
                              void* d_out, int out_size, void* d_ws, size_t ws_size,
                              hipStream_t stream) {
    const int*   q          = (const int*)d_in[0];
    const int*   a          = (const int*)d_in[1];
    const int*   next_q     = (const int*)d_in[2];
    const float* ques_table = (const float*)d_in[3];
    const float* skill_tab  = (const float*)d_in[4];
    const float* diff_tab   = (const float*)d_in[5];
    const float* area_tab   = (const float*)d_in[6];
    const int*   q2s        = (const int*)d_in[7];
    const int*   q2d        = (const int*)d_in[8];
    const int*   q2a        = (const int*)d_in[9];
    const float* Wq         = (const float*)d_in[10];
    const float* bq         = (const float*)d_in[11];
    float* out = (float*)d_out;

    const int NS = in_sizes[4] / 128;       // 2001
    const int pad_idx = NS - 1;             // 2000

    unsigned short* Wqb = (unsigned short*)d_ws;            // 2048*8 = 32 KiB
    unsigned short* T2  = Wqb + (size_t)2048 * 8;           // 2151*128 bf16

    h2kt_prep_wqb<<<8, 256, 0, stream>>>(Wq, Wqb);
    h2kt_prep_tables<<<135, 64, 0, stream>>>(skill_tab, diff_tab, area_tab, Wqb, T2);
    h2kt_fused<<<4096, 128, 0, stream>>>(q, a, next_q, ques_table,
                                         q2s, q2d, q2a, T2, Wqb, bq, out, pad_idx);
}

// Round 10
// 42.905 us; speedup vs baseline: 2.1365x; 1.0436x over previous
//
#include <hip/hip_runtime.h>
#include <hip/hip_bf16.h>

typedef float  f32x4  __attribute__((ext_vector_type(4)));
typedef short  s16x8  __attribute__((ext_vector_type(8)));

#define PIN_LOADS() asm volatile("" ::: "memory")

__device__ __forceinline__ unsigned short f2bf(float f) {
    unsigned int u = __float_as_uint(f);
    unsigned int rnd = 0x7fffu + ((u >> 16) & 1u);   // round-to-nearest-even
    return (unsigned short)((u + rnd) >> 16);
}

// acc += s * unpack_bf16x8(v)
__device__ __forceinline__ void bf8_fma(const s16x8 v, float s, f32x4& a0, f32x4& a1) {
    const uint4 u = *(const uint4*)&v;
    a0[0] += s * __uint_as_float(u.x << 16);
    a0[1] += s * __uint_as_float(u.x & 0xffff0000u);
    a0[2] += s * __uint_as_float(u.y << 16);
    a0[3] += s * __uint_as_float(u.y & 0xffff0000u);
    a1[0] += s * __uint_as_float(u.z << 16);
    a1[1] += s * __uint_as_float(u.z & 0xffff0000u);
    a1[2] += s * __uint_as_float(u.w << 16);
    a1[3] += s * __uint_as_float(u.w & 0xffff0000u);
}

// ONE prep kernel, three independent block ranges (no inter-range deps):
//  blocks [0,8)    : Wq f32 -> bf16 B-fragments (frag-linear Wqb)
//  blocks [8,42)   : T2[r] = table_row @ Wq^T (B-frags converted inline from Wq)
//  blocks [42,298) : desc[row] = {qq, sidx[0..7], diffRow, areaRow, a}  (48 B)
__global__ __launch_bounds__(256)
void h2kt_prep(const float* __restrict__ Wq,
               const float* __restrict__ skill, const float* __restrict__ diff,
               const float* __restrict__ area,
               const int* __restrict__ q, const int* __restrict__ next_q,
               const int* __restrict__ a_arr,
               const int* __restrict__ q2s, const int* __restrict__ q2d,
               const int* __restrict__ q2a,
               unsigned short* __restrict__ Wqb,
               unsigned short* __restrict__ T2,
               int* __restrict__ desc,
               int pad_idx)
{
    const int bid = blockIdx.x, tid = threadIdx.x;

    if (bid < 8) {
        // ---- Wqb: slot s holds Wq[jt*16+(sl&15)][kt*32+(sl>>4)*8 + i], i<8
        const int s  = bid * 256 + tid;              // 0..2047
        const int f  = s >> 6, sl = s & 63;
        const int jt = f >> 2, kt = f & 3;
        const int row = jt * 16 + (sl & 15);
        const int col = kt * 32 + (sl >> 4) * 8;
        const float4 w0 = *(const float4*)(Wq + row * 128 + col);
        const float4 w1 = *(const float4*)(Wq + row * 128 + col + 4);
        s16x8 v;
        v[0] = (short)f2bf(w0.x); v[1] = (short)f2bf(w0.y);
        v[2] = (short)f2bf(w0.z); v[3] = (short)f2bf(w0.w);
        v[4] = (short)f2bf(w1.x); v[5] = (short)f2bf(w1.y);
        v[6] = (short)f2bf(w1.z); v[7] = (short)f2bf(w1.w);
        *(s16x8*)(Wqb + (size_t)s * 8) = v;
    } else if (bid < 42) {
        // ---- T2: 4 independent 64-lane groups per block, 16 rows each
        const int lane = tid & 63;
        const int cl = lane & 15, grp = lane >> 4;
        const int row16 = ((bid - 8) * 4 + (tid >> 6)) * 16;   // 0..2160
        if (row16 > 2150) return;

        int srow = row16 + cl;
        if (srow > 2150) srow = 2150;
        const float* src = (srow < 2001) ? skill + (size_t)srow * 128
                         : (srow < 2101) ? diff + (size_t)(srow - 2001) * 128
                                         : area + (size_t)(srow - 2101) * 128;
        s16x8 afr[4];
        #pragma unroll
        for (int kt = 0; kt < 4; ++kt) {
            const float4 v0 = *(const float4*)(src + kt * 32 + grp * 8);
            const float4 v1 = *(const float4*)(src + kt * 32 + grp * 8 + 4);
            s16x8 v;
            v[0] = (short)f2bf(v0.x); v[1] = (short)f2bf(v0.y);
            v[2] = (short)f2bf(v0.z); v[3] = (short)f2bf(v0.w);
            v[4] = (short)f2bf(v1.x); v[5] = (short)f2bf(v1.y);
            v[6] = (short)f2bf(v1.z); v[7] = (short)f2bf(v1.w);
            afr[kt] = v;
        }
        #pragma unroll
        for (int jt = 0; jt < 8; ++jt) {
            f32x4 acc = {0.f, 0.f, 0.f, 0.f};
            #pragma unroll
            for (int kt = 0; kt < 4; ++kt) {
                // inline B-frag from Wq (no Wqb dependency within this kernel)
                const float* wp = Wq + (jt * 16 + cl) * 128 + kt * 32 + grp * 8;
                const float4 w0 = *(const float4*)(wp);
                const float4 w1 = *(const float4*)(wp + 4);
                s16x8 bf;
                bf[0] = (short)f2bf(w0.x); bf[1] = (short)f2bf(w0.y);
                bf[2] = (short)f2bf(w0.z); bf[3] = (short)f2bf(w0.w);
                bf[4] = (short)f2bf(w1.x); bf[5] = (short)f2bf(w1.y);
                bf[6] = (short)f2bf(w1.z); bf[7] = (short)f2bf(w1.w);
                acc = __builtin_amdgcn_mfma_f32_16x16x32_bf16(afr[kt], bf, acc, 0, 0, 0);
            }
            #pragma unroll
            for (int r = 0; r < 4; ++r) {
                const int orow = row16 + grp * 4 + r;
                if (orow < 2151) T2[(size_t)orow * 128 + jt * 16 + cl] = f2bf(acc[r]);
            }
        }
    } else {
        // ---- desc: pre-resolve the 2-level index chain to a linear record
        const int g = (bid - 42) * 256 + tid;        // 0..65535
        const int p = g & 32767;
        const bool isnq = (g >= 32768);
        const int qq = isnq ? next_q[p] : q[p];
        const int4 s03 = *(const int4*)(q2s + (size_t)qq * 8);
        const int4 s47 = *(const int4*)(q2s + (size_t)qq * 8 + 4);
        const int di = q2d[qq];
        const int ai = q2a[qq];
        const int av = isnq ? 1 : a_arr[p];
        int4* d = (int4*)(desc + (size_t)g * 12);
        d[0] = make_int4(qq, s03.x, s03.y, s03.z);
        d[1] = make_int4(s03.w, s47.x, s47.y, s47.z);
        d[2] = make_int4(s47.w, 2001 + di, 2101 + ai, av);
    }
}

// Fused main: R4 structure + LDS union; index chain replaced by linear desc
// reads (1 L2-hot coalesced level instead of 3 dependent gather levels).
__global__ __launch_bounds__(128, 4)
void h2kt_fused(const int* __restrict__ desc,
                const float* __restrict__ ques_table,
                const unsigned short* __restrict__ T2,
                const unsigned short* __restrict__ Wqb,
                const float* __restrict__ bq,
                float* __restrict__ out,
                int pad_idx)
{
    // Q (bf16 16x136) and D (f32 16x132) live in disjoint phases -> union.
    __shared__ __align__(16) unsigned char U[16 * 132 * 4];   // 8448 B
    unsigned short* Q = (unsigned short*)U;    // stride 136 shorts
    float*          D = (float*)U;             // stride 132 floats

    const int tid  = threadIdx.x;
    const int w    = tid >> 6;
    const int lane = tid & 63;
    const int cl   = lane & 15;
    const int grp  = lane >> 4;
    const int g0   = blockIdx.x * 16;          // global row base, 0..65520
    const int base = g0 & 32767;
    const bool isnq = (g0 >= 32768);
    const float wq_ = isnq ? 0.0625f : 0.25f;
    const float wr_ = isnq ? 0.3125f : 0.25f;

    // ---- descriptor loads (linear, L2-hot) ----
    const int r2 = lane >> 5;
    const int c  = lane & 31;
    int qqv[4];
    #pragma unroll
    for (int p = 0; p < 4; ++p)
        qqv[p] = desc[(size_t)(g0 + w * 8 + p * 2 + r2) * 12];

    const int4* D0 = (const int4*)(desc + (size_t)(g0 + w * 8 + grp) * 12);
    const int4* D1 = (const int4*)(desc + (size_t)(g0 + w * 8 + 4 + grp) * 12);
    const int4 a0i = D0[0], a1i = D0[1], a2i = D0[2];
    const int4 b0i = D1[0], b1i = D1[1], b2i = D1[2];

    // ---- qe rows (HBM latency) issued ASAP ----
    f32x4 qv[4];
    #pragma unroll
    for (int p = 0; p < 4; ++p)
        qv[p] = *(const f32x4*)(ques_table + (size_t)qqv[p] * 128 + c * 4);

    const int sa[8] = {a0i.y, a0i.z, a0i.w, a1i.x, a1i.y, a1i.z, a1i.w, a2i.x};
    const int sb[8] = {b0i.y, b0i.z, b0i.w, b1i.x, b1i.y, b1i.z, b1i.w, b2i.x};
    const int av0 = a2i.w, av1 = b2i.w;

    // ---- batch 0: pass-0 T2 slices ----
    s16x8 t0[10];
    #pragma unroll
    for (int i = 0; i < 8; ++i)
        t0[i] = *(const s16x8*)(T2 + (size_t)sa[i] * 128 + cl * 8);
    t0[8] = *(const s16x8*)(T2 + (size_t)a2i.y * 128 + cl * 8);
    t0[9] = *(const s16x8*)(T2 + (size_t)a2i.z * 128 + cl * 8);
    PIN_LOADS();

    // ---- qe -> bf16(wq*qe) -> LDS Q ----
    #pragma unroll
    for (int p = 0; p < 4; ++p) {
        ushort4 o;
        o.x = f2bf(wq_ * qv[p][0]); o.y = f2bf(wq_ * qv[p][1]);
        o.z = f2bf(wq_ * qv[p][2]); o.w = f2bf(wq_ * qv[p][3]);
        *(ushort4*)(Q + (size_t)(w * 8 + p * 2 + r2) * 136 + c * 4) = o;
    }

    // ---- batch 1: pass-1 T2 slices ----
    s16x8 t1[10];
    #pragma unroll
    for (int i = 0; i < 8; ++i)
        t1[i] = *(const s16x8*)(T2 + (size_t)sb[i] * 128 + cl * 8);
    t1[8] = *(const s16x8*)(T2 + (size_t)b2i.y * 128 + cl * 8);
    t1[9] = *(const s16x8*)(T2 + (size_t)b2i.z * 128 + cl * 8);
    PIN_LOADS();

    // ---- combine ----
    int cnt0 = 0, cnt1 = 0;
    #pragma unroll
    for (int i = 0; i < 8; ++i) { cnt0 += (sa[i] != pad_idx); cnt1 += (sb[i] != pad_idx); }
    const float cs0 = cnt0 > 0 ? wr_ / (float)cnt0 : 0.f;
    const float cs1 = cnt1 > 0 ? wr_ / (float)cnt1 : 0.f;

    f32x4 restA[2], restB[2];
    {
        f32x4 a0 = {0.f,0.f,0.f,0.f}, a1 = {0.f,0.f,0.f,0.f};
        #pragma unroll
        for (int i = 0; i < 8; ++i) bf8_fma(t0[i], (sa[i] != pad_idx) ? cs0 : 0.f, a0, a1);
        bf8_fma(t0[8], wr_, a0, a1);
        bf8_fma(t0[9], wr_, a0, a1);
        restA[0] = a0; restB[0] = a1;
    }
    {
        f32x4 a0 = {0.f,0.f,0.f,0.f}, a1 = {0.f,0.f,0.f,0.f};
        #pragma unroll
        for (int i = 0; i < 8; ++i) bf8_fma(t1[i], (sb[i] != pad_idx) ? cs1 : 0.f, a0, a1);
        bf8_fma(t1[8], wr_, a0, a1);
        bf8_fma(t1[9], wr_, a0, a1);
        restA[1] = a0; restB[1] = a1;
    }

    __syncthreads();   // Q ready

    s16x8 afr[4];
    #pragma unroll
    for (int kt = 0; kt < 4; ++kt)
        afr[kt] = *(const s16x8*)(Q + (size_t)cl * 136 + kt * 32 + grp * 8);

    __syncthreads();   // Q consumed -> D may overwrite the union

    #pragma unroll
    for (int jt2 = 0; jt2 < 4; ++jt2) {
        const int jt = w * 4 + jt2;
        f32x4 acc = {0.f, 0.f, 0.f, 0.f};
        #pragma unroll
        for (int kt = 0; kt < 4; ++kt) {
            const s16x8 bf = *(const s16x8*)(Wqb + ((size_t)(jt * 4 + kt) * 64 + lane) * 8);
            acc = __builtin_amdgcn_mfma_f32_16x16x32_bf16(afr[kt], bf, acc, 0, 0, 0);
        }
        #pragma unroll
        for (int r = 0; r < 4; ++r)
            D[(size_t)(grp * 4 + r) * 132 + jt * 16 + cl] = acc[r];
    }

    __syncthreads();   // D ready

    const f32x4 bq0 = *(const f32x4*)(bq + cl * 8);
    const f32x4 bq1 = *(const f32x4*)(bq + cl * 8 + 4);
    const f32x4 z = {0.f, 0.f, 0.f, 0.f};
    #pragma unroll
    for (int p = 0; p < 2; ++p) {
        const int row = w * 8 + p * 4 + grp;
        const f32x4 d0 = *(const f32x4*)(D + (size_t)row * 132 + cl * 8);
        const f32x4 d1 = *(const f32x4*)(D + (size_t)row * 132 + cl * 8 + 4);
        const f32x4 v0 = d0 + restA[p] + bq0;
        const f32x4 v1 = d1 + restB[p] + bq1;
        const size_t orow = (size_t)(base + row);
        const int avv = (p == 0) ? av0 : av1;
        if (!isnq) {
            const bool on = (avv != 0);
            *(f32x4*)(out + orow * 384 + cl * 8)           = on ? v0 : z;
            *(f32x4*)(out + orow * 384 + cl * 8 + 4)       = on ? v1 : z;
            *(f32x4*)(out + orow * 384 + 128 + cl * 8)     = on ? z : v0;
            *(f32x4*)(out + orow * 384 + 128 + cl * 8 + 4) = on ? z : v1;
        } else {
            *(f32x4*)(out + orow * 384 + 256 + cl * 8)     = v0;
            *(f32x4*)(out + orow * 384 + 256 + cl * 8 + 4) = v1;
        }
    }
}

extern "C" void kernel_launch(void* const* d_in, const int* in_sizes, int n_in,
                              void* d_out, int out_size, void* d_ws, size_t ws_size,
                              hipStream_t stream) {
    const int*   q          = (const int*)d_in[0];
    const int*   a          = (const int*)d_in[1];
    const int*   next_q     = (const int*)d_in[2];
    const float* ques_table = (const float*)d_in[3];
    const float* skill_tab  = (const float*)d_in[4];
    const float* diff_tab   = (const float*)d_in[5];
    const float* area_tab   = (const float*)d_in[6];
    const int*   q2s        = (const int*)d_in[7];
    const int*   q2d        = (const int*)d_in[8];
    const int*   q2a        = (const int*)d_in[9];
    const float* Wq         = (const float*)d_in[10];
    const float* bq         = (const float*)d_in[11];
    float* out = (float*)d_out;

    const int NS = in_sizes[4] / 128;       // 2001
    const int pad_idx = NS - 1;             // 2000

    // ws: desc (65536*48B = 3 MiB) | Wqb (32 KiB) | T2 (2151*256B)
    int*            descp = (int*)d_ws;
    unsigned short* Wqb   = (unsigned short*)((char*)d_ws + (size_t)65536 * 48);
    unsigned short* T2    = Wqb + (size_t)2048 * 8;

    h2kt_prep<<<298, 256, 0, stream>>>(Wq, skill_tab, diff_tab, area_tab,
                                       q, next_q, a, q2s, q2d, q2a,
                                       Wqb, T2, descp, pad_idx);
    h2kt_fused<<<4096, 128, 0, stream>>>(descp, ques_table, T2, Wqb, bq, out, pad_idx);
}